// Round 14
// baseline (250.397 us; speedup 1.0000x reference)
//
#include <hip/hip_runtime.h>
#include <stdint.h>

typedef __bf16 bf16x8 __attribute__((ext_vector_type(8)));
typedef float f32x4 __attribute__((ext_vector_type(4)));
typedef float f32x16 __attribute__((ext_vector_type(16)));
typedef float float4v __attribute__((ext_vector_type(4)));
typedef unsigned short u16x4 __attribute__((ext_vector_type(4)));
typedef unsigned short u16x8 __attribute__((ext_vector_type(8)));
typedef unsigned int u32x4v __attribute__((ext_vector_type(4)));

#define DEVI __device__ __forceinline__

static constexpr int Bv = 2, Sv = 4096, Ev = 512, Hv = 8, Dv = 64;
static constexpr int Mv = Bv * Sv;   // 8192
static constexpr int N3v = 3 * Ev;   // 1536
static constexpr float QSCALE = 0.125f * 1.4426950408889634f;  // exp2-domain
static constexpr float C0 = -8.0f;   // uniform exp2 offset (cancels in o/l)

#if __has_builtin(__builtin_amdgcn_exp2f)
#define EXP2F(x) __builtin_amdgcn_exp2f(x)
#else
#define EXP2F(x) exp2f(x)
#endif

DEVI unsigned short f2bf(float f) {
    unsigned int u = __builtin_bit_cast(unsigned int, f);
    u += 0x7fffu + ((u >> 16) & 1u);
    return (unsigned short)(u >> 16);
}

DEVI float b2f(unsigned short u) {
    return __builtin_bit_cast(float, (unsigned int)u << 16);
}

DEVI unsigned int cvtpk(float lo, float hi) {
    unsigned int r;
    asm("v_cvt_pk_bf16_f32 %0, %1, %2" : "=v"(r) : "v"(lo), "v"(hi));
    return r;
}

DEVI void gload16(const void* src, void* lds) {
    __builtin_amdgcn_global_load_lds(
        (const __attribute__((address_space(1))) unsigned int*)src,
        (__attribute__((address_space(3))) unsigned int*)lds,
        16, 0, 0);
}

// ---------------- fused prep: x->bf16 convert + both weight transposes ----------------
// blocks [0,2048): convert; [2048,2816): qkv_w tconv (512x1536); [2816,3072): out_w (512x512)
__global__ __launch_bounds__(256) void k_prep(const float* __restrict__ x,
                                              unsigned short* __restrict__ xb,
                                              const float* __restrict__ qkv_w,
                                              unsigned short* __restrict__ wqkvT,
                                              const float* __restrict__ out_w,
                                              unsigned short* __restrict__ owT) {
    __shared__ float lds[32][36];
    int blk = blockIdx.x;
    int t = threadIdx.x;
    if (blk < 2048) {
        int n4 = Mv * Ev / 4;
        int i = blk * 256 + t;
        int stride = 2048 * 256;
        for (; i < n4; i += stride) {
            float4v v = ((const float4v*)x)[i];
            u16x4 o;
            o[0] = f2bf(v[0]); o[1] = f2bf(v[1]); o[2] = f2bf(v[2]); o[3] = f2bf(v[3]);
            ((u16x4*)xb)[i] = o;
        }
        return;
    }
    const float* in;
    unsigned short* out;
    int K = 512, N, tile;
    if (blk < 2816) { in = qkv_w; out = wqkvT; N = 1536; tile = blk - 2048; }
    else            { in = out_w; out = owT;   N = 512;  tile = blk - 2816; }
    int tilesN = N >> 5;
    int tn = tile % tilesN, tk = tile / tilesN;
    int k0 = tk << 5, n0 = tn << 5;
    int r = t >> 3, c4 = (t & 7) << 2;
    float4v v = *(const float4v*)(in + (size_t)(k0 + r) * N + n0 + c4);
    *(float4v*)&lds[r][c4] = v;
    __syncthreads();
    int nn = t >> 3, kc = (t & 7) << 2;
    u16x4 o;
#pragma unroll
    for (int j = 0; j < 4; ++j) o[j] = f2bf(lds[kc + j][nn]);
    *(u16x4*)(out + (size_t)(n0 + nn) * K + k0 + kc) = o;
}

// ---------------- GEMM 128x128 tile, BK=64, bf16 MFMA ----------------
// EPI 0: QKV scatter (V written TRANSPOSED [bh][d][s]). EPI 1: proj+residual -> bf16 tmp.
template <int EPI>
__global__ __launch_bounds__(256) void k_gemm(
    const unsigned short* __restrict__ A, const unsigned short* __restrict__ Bt,
    int M, int N, int K, const float* __restrict__ bias,
    unsigned short* __restrict__ Qb, unsigned short* __restrict__ Kb,
    unsigned short* __restrict__ Vtb,
    const float* __restrict__ xres, unsigned short* __restrict__ outb) {
    __shared__ char smem[32768];
    char* As = smem;
    char* Bs = smem + 16384;
    int nbt = N >> 7;
    int mb = blockIdx.x / nbt, nbi = blockIdx.x % nbt;
    int m0 = mb << 7, n0 = nbi << 7;
    int tid = threadIdx.x, lane = tid & 63, wave = tid >> 6;
    int wr = wave >> 1, wc = wave & 1;

    f32x4 acc[4][4];
    f32x4 zero = {0.f, 0.f, 0.f, 0.f};
#pragma unroll
    for (int a = 0; a < 4; ++a)
#pragma unroll
        for (int b = 0; b < 4; ++b) acc[a][b] = zero;

    for (int kt = 0; kt < K; kt += 64) {
        __syncthreads();
#pragma unroll
        for (int j = 0; j < 4; ++j) {
            int la = (((wave << 2) + j) << 10) + lane * 16;
            int r = la >> 7, cb = la & 127;
            int cbs = cb ^ ((r & 7) << 4);
            gload16((const char*)(A + (size_t)(m0 + r) * K + kt) + cbs,
                    As + (((wave << 2) + j) << 10));
            gload16((const char*)(Bt + (size_t)(n0 + r) * K + kt) + cbs,
                    Bs + (((wave << 2) + j) << 10));
        }
        asm volatile("s_waitcnt vmcnt(0)" ::: "memory");
        __syncthreads();

        bf16x8 af[4][2], bfr[4][2];
#pragma unroll
        for (int rf = 0; rf < 4; ++rf)
#pragma unroll
            for (int c = 0; c < 2; ++c) {
                int row = (wr << 6) + (rf << 4) + (lane & 15);
                int col = (c << 6) + ((lane >> 4) << 4);
                af[rf][c] = *(const bf16x8*)(As + row * 128 + (col ^ ((row & 7) << 4)));
                int rowb = (wc << 6) + (rf << 4) + (lane & 15);
                bfr[rf][c] = *(const bf16x8*)(Bs + rowb * 128 + (col ^ ((rowb & 7) << 4)));
            }
#pragma unroll
        for (int rf = 0; rf < 4; ++rf)
#pragma unroll
            for (int nf = 0; nf < 4; ++nf)
#pragma unroll
                for (int c = 0; c < 2; ++c)
                    acc[rf][nf] = __builtin_amdgcn_mfma_f32_16x16x32_bf16(
                        af[rf][c], bfr[nf][c], acc[rf][nf], 0, 0, 0);
    }

#pragma unroll
    for (int rf = 0; rf < 4; ++rf)
#pragma unroll
        for (int nf = 0; nf < 4; ++nf) {
            int row0 = m0 + (wr << 6) + (rf << 4) + ((lane >> 4) << 2);
            int col = n0 + (wc << 6) + (nf << 4) + (lane & 15);
            float bv = bias[col];
            if (EPI == 0) {
                int reg = col >> 9, hd = col & 511;
                int h = hd >> 6, d = hd & 63;
                int b = row0 >> 12, s0 = row0 & 4095;
                if (reg == 2) {
                    u16x4 o4;
#pragma unroll
                    for (int i = 0; i < 4; ++i) o4[i] = f2bf(acc[rf][nf][i] + bv);
                    *(u16x4*)(Vtb + ((size_t)((b << 3) + h) * 64 + d) * 4096 + s0) = o4;
                } else {
#pragma unroll
                    for (int i = 0; i < 4; ++i) {
                        float v = acc[rf][nf][i] + bv;
                        size_t idx = ((size_t)((b << 3) + h) * Sv + s0 + i) * Dv + d;
                        if (reg == 0) Qb[idx] = f2bf(v * QSCALE);
                        else          Kb[idx] = f2bf(v);
                    }
                }
            } else {
#pragma unroll
                for (int i = 0; i < 4; ++i) {
                    int row = row0 + i;
                    float v = acc[rf][nf][i] + bv + xres[(size_t)row * N + col];
                    outb[(size_t)row * N + col] = f2bf(v);
                }
            }
        }
}

// ---------------- flash attention: 64q/wave, shared staging, counted vmcnt -----
// KV-split x2 (2048 kv/block = 64 chunks of 32). Per chunk: 8 gload16 split 2/wave;
// vmcnt(2)+s_barrier; compute. 3 LDS buffers x (K 4KB [32kv][128B] | V 4KB [64d][64B]).
// Fused merge: blocks sharing (bh,qblk) race on a flag; second arriver merges
// both halves into ctx (threadFenceReduction pattern; o0+o1 is order-invariant).
// NOTE: min-waves stays 2 — forcing 4 caps VGPR at 128 -> scratch spills (R7).
__global__ __launch_bounds__(256, 2) void k_attn(const unsigned short* __restrict__ Qb,
                                                 const unsigned short* __restrict__ Kb,
                                                 const unsigned short* __restrict__ Vtb,
                                                 unsigned short* __restrict__ po,
                                                 float* __restrict__ pl,
                                                 int* __restrict__ flags,
                                                 unsigned short* __restrict__ ctx) {
    __shared__ char smem[24576];
    __shared__ int who;
    int bid = blockIdx.x;
    int wg = ((bid & 7) << 6) + (bid >> 3);  // bijective XCD swizzle (nwg=512)
    int half = wg & 1, qblk = (wg >> 1) & 15, bh = wg >> 5;
    int tid = threadIdx.x, lane = tid & 63, wave = tid >> 6;
    int l31 = lane & 31, hh = lane >> 5;
    int qbase = (qblk << 8) + (wave << 6);  // 256 q/block, 64 q/wave
    int kvbase = half << 11;                // 2048 kv per block
    const int NCH = 64;                     // 64 chunks of 32 kv

    const char* Kbase = (const char*)(Kb + (size_t)bh * Sv * Dv + (size_t)kvbase * Dv);
    const char* Vtbase = (const char*)(Vtb + (size_t)bh * Dv * Sv + kvbase);

    bf16x8 qf[2][4];
#pragma unroll
    for (int qs = 0; qs < 2; ++qs)
#pragma unroll
        for (int tp = 0; tp < 4; ++tp)
            qf[qs][tp] = *(const bf16x8*)(Qb + ((size_t)bh * Sv + qbase + (qs << 5) + l31) * Dv +
                                          (tp << 4) + (hh << 3));

    const char* src0;
    const char* src1;
    size_t st0, st1;
    int d0, d1;
    {
        int j0 = wave << 1, j1 = j0 + 1;
        if (j0 < 4) {
            int lo0 = (j0 << 10) + lane * 16, r0 = lo0 >> 7, cb0 = lo0 & 127;
            src0 = Kbase + (size_t)r0 * 128 + (cb0 ^ ((r0 & 7) << 4));
            st0 = 4096; d0 = j0 << 10;
            int lo1 = (j1 << 10) + lane * 16, r1 = lo1 >> 7, cb1 = lo1 & 127;
            src1 = Kbase + (size_t)r1 * 128 + (cb1 ^ ((r1 & 7) << 4));
            st1 = 4096; d1 = j1 << 10;
        } else {
            int lo0 = ((j0 - 4) << 10) + lane * 16, r0 = lo0 >> 6, cb0 = lo0 & 63;
            src0 = Vtbase + (size_t)r0 * 8192 + (cb0 ^ ((r0 & 6) << 3));
            st0 = 64; d0 = 4096 + ((j0 - 4) << 10);
            int lo1 = ((j1 - 4) << 10) + lane * 16, r1 = lo1 >> 6, cb1 = lo1 & 63;
            src1 = Vtbase + (size_t)r1 * 8192 + (cb1 ^ ((r1 & 6) << 3));
            st1 = 64; d1 = 4096 + ((j1 - 4) << 10);
        }
    }

    int koff[4], voff[4];
#pragma unroll
    for (int tp = 0; tp < 4; ++tp)
        koff[tp] = l31 * 128 + (((tp << 5) + (hh << 4)) ^ ((l31 & 7) << 4));
#pragma unroll
    for (int tl = 0; tl < 2; ++tl)
#pragma unroll
        for (int dt = 0; dt < 2; ++dt) {
            int row = (dt << 5) + l31;
            int col = (tl << 5) + (hh << 4);
            voff[tl * 2 + dt] = row * 64 + (col ^ ((row & 6) << 3));
        }

    f32x16 o[2][2];
#pragma unroll
    for (int qs = 0; qs < 2; ++qs)
#pragma unroll
        for (int dt = 0; dt < 2; ++dt)
#pragma unroll
            for (int r = 0; r < 16; ++r) o[qs][dt][r] = 0.f;
    float lsum[2] = {0.f, 0.f};

    gload16(src0, smem + d0);
    gload16(src1, smem + d1);
    gload16(src0 + st0, smem + 8192 + d0);
    gload16(src1 + st1, smem + 8192 + d1);

#define COMPUTE_CHUNK(KSP, VSP)                                                          \
    {                                                                                    \
        bf16x8 kf[4], vf[4];                                                             \
        _Pragma("unroll") for (int tp = 0; tp < 4; ++tp)                                 \
            kf[tp] = *(const bf16x8*)((KSP) + koff[tp]);                                 \
        _Pragma("unroll") for (int i = 0; i < 4; ++i)                                    \
            vf[i] = *(const bf16x8*)((VSP) + voff[i]);                                   \
        _Pragma("unroll") for (int qs = 0; qs < 2; ++qs) {                               \
            f32x16 sc;                                                                   \
            _Pragma("unroll") for (int r = 0; r < 16; ++r) sc[r] = C0;                   \
            __builtin_amdgcn_s_setprio(1);                                               \
            _Pragma("unroll") for (int tp = 0; tp < 4; ++tp)                             \
                sc = __builtin_amdgcn_mfma_f32_32x32x16_bf16(kf[tp], qf[qs][tp], sc, 0, 0, 0); \
            __builtin_amdgcn_s_setprio(0);                                               \
            _Pragma("unroll") for (int r = 0; r < 16; ++r) sc[r] = EXP2F(sc[r]);         \
            float s0 = (sc[0] + sc[1]) + (sc[2] + sc[3]);                                \
            float s1 = (sc[4] + sc[5]) + (sc[6] + sc[7]);                                \
            float s2 = (sc[8] + sc[9]) + (sc[10] + sc[11]);                              \
            float s3 = (sc[12] + sc[13]) + (sc[14] + sc[15]);                            \
            lsum[qs] += (s0 + s1) + (s2 + s3);                                           \
            unsigned int W[8];                                                           \
            _Pragma("unroll") for (int i = 0; i < 8; ++i)                                \
                W[i] = cvtpk(sc[2 * i], sc[2 * i + 1]);                                  \
            _Pragma("unroll") for (int tl = 0; tl < 2; ++tl) {                           \
                unsigned int a1 = W[4 * tl], b1 = W[4 * tl + 2];                         \
                unsigned int a2 = W[4 * tl + 1], b2 = W[4 * tl + 3];                     \
                asm volatile("v_permlane32_swap_b32 %0, %1" : "+v"(a1), "+v"(b1));       \
                asm volatile("v_permlane32_swap_b32 %0, %1" : "+v"(a2), "+v"(b2));       \
                u32x4v uu;                                                               \
                uu[0] = a1; uu[1] = a2; uu[2] = b1; uu[3] = b2;                          \
                bf16x8 pf = __builtin_bit_cast(bf16x8, uu);                              \
                __builtin_amdgcn_s_setprio(1);                                           \
                _Pragma("unroll") for (int dt = 0; dt < 2; ++dt)                         \
                    o[qs][dt] = __builtin_amdgcn_mfma_f32_32x32x16_bf16(                 \
                        vf[tl * 2 + dt], pf, o[qs][dt], 0, 0, 0);                        \
                __builtin_amdgcn_s_setprio(0);                                           \
            }                                                                            \
        }                                                                                \
    }

    int cur = 0;
    for (int kt = 0; kt < NCH - 1; ++kt) {
        asm volatile("s_waitcnt vmcnt(2)\n\ts_barrier" ::: "memory");
        if (kt + 2 < NCH) {
            int tb = cur + 2; if (tb >= 3) tb -= 3;
            gload16(src0 + (size_t)(kt + 2) * st0, smem + tb * 8192 + d0);
            gload16(src1 + (size_t)(kt + 2) * st1, smem + tb * 8192 + d1);
        }
        char* cbuf = smem + cur * 8192;
        COMPUTE_CHUNK(cbuf, cbuf + 4096);
        cur = (cur + 1 == 3) ? 0 : cur + 1;
    }
    asm volatile("s_waitcnt vmcnt(0)\n\ts_barrier" ::: "memory");
    {
        char* cbuf = smem + cur * 8192;
        COMPUTE_CHUNK(cbuf, cbuf + 4096);
    }
#undef COMPUTE_CHUNK

#pragma unroll
    for (int qs = 0; qs < 2; ++qs) {
        float ls = lsum[qs] + __shfl_xor(lsum[qs], 32, 64);
        int qrow = qbase + (qs << 5) + l31;
        if (!hh) pl[((size_t)half * 16 + bh) * Sv + qrow] = ls;
        size_t obase = (((size_t)half * 16 + bh) * Sv + qrow) * 64;
#pragma unroll
        for (int dt = 0; dt < 2; ++dt)
#pragma unroll
            for (int rp = 0; rp < 8; ++rp) {
                int r = rp << 1;
                int d = (dt << 5) + (r & 3) + ((r >> 2) << 3) + (hh << 2);
                unsigned int w = cvtpk(o[qs][dt][r], o[qs][dt][r + 1]);
                *(unsigned int*)(po + obase + d) = w;
            }
    }

    // ---- fused merge: second arriver for (bh,qblk) combines both halves ----
    __threadfence();
    __syncthreads();
    if (tid == 0) who = atomicAdd(&flags[(bh << 4) + qblk], 1);
    __syncthreads();
    if (who == 1) {
        __threadfence();
        int s = (qblk << 8) + tid;
        size_t r0 = ((size_t)bh * Sv + s) * 64;
        size_t r1 = r0 + (size_t)16 * Sv * 64;
        float inv = 1.f / (pl[(size_t)bh * Sv + s] + pl[(size_t)16 * Sv + bh * Sv + s]);
        int b = bh >> 3, h = bh & 7;
        size_t cb = ((size_t)b * Sv + s) * Ev + (h << 6);
#pragma unroll
        for (int j = 0; j < 8; ++j) {
            u16x8 pa = *(const u16x8*)(po + r0 + j * 8);
            u16x8 pb2 = *(const u16x8*)(po + r1 + j * 8);
            u32x4v w;
#pragma unroll
            for (int m = 0; m < 4; ++m) {
                float lo = (b2f(pa[2 * m]) + b2f(pb2[2 * m])) * inv;
                float hi = (b2f(pa[2 * m + 1]) + b2f(pb2[2 * m + 1])) * inv;
                w[m] = cvtpk(lo, hi);
            }
            *(u32x4v*)(ctx + cb + j * 8) = w;
        }
    }
}

// ---------------- LayerNorm (1 wave / row of 512, bf16 in, fp32 out) ----------------
__global__ __launch_bounds__(256) void k_ln(const unsigned short* __restrict__ in,
                                            const float* __restrict__ g,
                                            const float* __restrict__ bta,
                                            float* __restrict__ out) {
    int wave = threadIdx.x >> 6, lane = threadIdx.x & 63;
    size_t row = (size_t)blockIdx.x * 4 + wave;
    u16x8 raw = *(const u16x8*)(in + row * 512 + lane * 8);
    float v[8];
    float s = 0.f, q = 0.f;
#pragma unroll
    for (int j = 0; j < 8; ++j) {
        v[j] = b2f(raw[j]);
        s += v[j];
        q += v[j] * v[j];
    }
#pragma unroll
    for (int off = 1; off < 64; off <<= 1) {
        s += __shfl_xor(s, off, 64);
        q += __shfl_xor(q, off, 64);
    }
    float mu = s * (1.f / 512.f);
    float var = q * (1.f / 512.f) - mu * mu;
    float rs = rsqrtf(var + 1e-5f);
    int c = lane * 8;
    float4v o0, o1;
#pragma unroll
    for (int j = 0; j < 4; ++j) {
        o0[j] = (v[j] - mu) * rs * g[c + j] + bta[c + j];
        o1[j] = (v[4 + j] - mu) * rs * g[c + 4 + j] + bta[c + 4 + j];
    }
    *(float4v*)(out + row * 512 + c) = o0;
    *(float4v*)(out + row * 512 + c + 4) = o1;
}

extern "C" void kernel_launch(void* const* d_in, const int* in_sizes, int n_in,
                              void* d_out, int out_size, void* d_ws, size_t ws_size,
                              hipStream_t stream) {
    const float* x     = (const float*)d_in[0];
    const float* qkv_w = (const float*)d_in[1];
    const float* qkv_b = (const float*)d_in[2];
    const float* out_w = (const float*)d_in[3];
    const float* out_b = (const float*)d_in[4];
    const float* ln_g  = (const float*)d_in[5];
    const float* ln_b  = (const float*)d_in[6];
    float* out = (float*)d_out;
    char* ws = (char*)d_ws;

    // layout (peak ~45 MB):
    unsigned short* owT   = (unsigned short*)(ws);              // 0.5 MB  [until gemm1]
    unsigned short* wqkvT = (unsigned short*)(ws + 524288);     // 1.5 MB  [until gemm0]
    unsigned short* Qb    = (unsigned short*)(ws + 2097152);    // 8 MB    [until attn]
    unsigned short* Kb    = (unsigned short*)(ws + 10485760);   // 8 MB    [until attn]
    unsigned short* Vtb   = (unsigned short*)(ws + 18874368);   // 8 MB    [until attn]
    unsigned short* xb    = (unsigned short*)(ws + 27262976);   // 8 MB    [until gemm0]
    unsigned short* po    = (unsigned short*)(ws + 27262976);   // 16 MB   [attn, over xb]
    float* pl             = (float*)(ws + 60817408);            // 0.5 MB
    int* flags            = (int*)(ws + 61341696);              // 1 KB (zeroed each launch)
    unsigned short* ctxb  = (unsigned short*)(ws + 2097152);    // 8 MB    [attn..gemm1, over Qb]
    unsigned short* tmpb  = (unsigned short*)(ws + 10485760);   // 8 MB    [gemm1..ln, over Kb]

    hipMemsetAsync(flags, 0, 1024, stream);
    k_prep<<<3072, 256, 0, stream>>>(x, xb, qkv_w, wqkvT, out_w, owT);
    k_gemm<0><<<(Mv / 128) * (N3v / 128), 256, 0, stream>>>(
        xb, wqkvT, Mv, N3v, Ev, qkv_b, Qb, Kb, Vtb, nullptr, nullptr);
    k_attn<<<512, 256, 0, stream>>>(Qb, Kb, Vtb, po, pl, flags, ctxb);
    k_gemm<1><<<(Mv / 128) * (Ev / 128), 256, 0, stream>>>(
        ctxb, owT, Mv, Ev, Ev, out_b, nullptr, nullptr, nullptr, x, tmpb);
    k_ln<<<Mv / 4, 256, 0, stream>>>(tmpb, ln_g, ln_b, out);
}

// Round 15
// 142.902 us; speedup vs baseline: 1.7522x; 1.7522x over previous
//
#include <hip/hip_runtime.h>
#include <stdint.h>

typedef __bf16 bf16x8 __attribute__((ext_vector_type(8)));
typedef float f32x4 __attribute__((ext_vector_type(4)));
typedef float f32x16 __attribute__((ext_vector_type(16)));
typedef float float4v __attribute__((ext_vector_type(4)));
typedef unsigned short u16x4 __attribute__((ext_vector_type(4)));
typedef unsigned short u16x8 __attribute__((ext_vector_type(8)));
typedef unsigned int u32x4v __attribute__((ext_vector_type(4)));

#define DEVI __device__ __forceinline__

static constexpr int Bv = 2, Sv = 4096, Ev = 512, Hv = 8, Dv = 64;
static constexpr int Mv = Bv * Sv;   // 8192
static constexpr int N3v = 3 * Ev;   // 1536
static constexpr float QSCALE = 0.125f * 1.4426950408889634f;  // exp2-domain
static constexpr float C0 = -8.0f;   // uniform exp2 offset (cancels in o/l)

#if __has_builtin(__builtin_amdgcn_exp2f)
#define EXP2F(x) __builtin_amdgcn_exp2f(x)
#else
#define EXP2F(x) exp2f(x)
#endif

DEVI unsigned short f2bf(float f) {
    unsigned int u = __builtin_bit_cast(unsigned int, f);
    u += 0x7fffu + ((u >> 16) & 1u);
    return (unsigned short)(u >> 16);
}

DEVI float b2f(unsigned short u) {
    return __builtin_bit_cast(float, (unsigned int)u << 16);
}

DEVI unsigned int cvtpk(float lo, float hi) {
    unsigned int r;
    asm("v_cvt_pk_bf16_f32 %0, %1, %2" : "=v"(r) : "v"(lo), "v"(hi));
    return r;
}

DEVI void gload16(const void* src, void* lds) {
    __builtin_amdgcn_global_load_lds(
        (const __attribute__((address_space(1))) unsigned int*)src,
        (__attribute__((address_space(3))) unsigned int*)lds,
        16, 0, 0);
}

// ---------------- fused prep: x->bf16 convert + both weight transposes ----------------
// blocks [0,2048): convert; [2048,2816): qkv_w tconv (512x1536); [2816,3072): out_w (512x512)
__global__ __launch_bounds__(256) void k_prep(const float* __restrict__ x,
                                              unsigned short* __restrict__ xb,
                                              const float* __restrict__ qkv_w,
                                              unsigned short* __restrict__ wqkvT,
                                              const float* __restrict__ out_w,
                                              unsigned short* __restrict__ owT) {
    __shared__ float lds[32][36];
    int blk = blockIdx.x;
    int t = threadIdx.x;
    if (blk < 2048) {
        int n4 = Mv * Ev / 4;
        int i = blk * 256 + t;
        int stride = 2048 * 256;
        for (; i < n4; i += stride) {
            float4v v = ((const float4v*)x)[i];
            u16x4 o;
            o[0] = f2bf(v[0]); o[1] = f2bf(v[1]); o[2] = f2bf(v[2]); o[3] = f2bf(v[3]);
            ((u16x4*)xb)[i] = o;
        }
        return;
    }
    const float* in;
    unsigned short* out;
    int K = 512, N, tile;
    if (blk < 2816) { in = qkv_w; out = wqkvT; N = 1536; tile = blk - 2048; }
    else            { in = out_w; out = owT;   N = 512;  tile = blk - 2816; }
    int tilesN = N >> 5;
    int tn = tile % tilesN, tk = tile / tilesN;
    int k0 = tk << 5, n0 = tn << 5;
    int r = t >> 3, c4 = (t & 7) << 2;
    float4v v = *(const float4v*)(in + (size_t)(k0 + r) * N + n0 + c4);
    *(float4v*)&lds[r][c4] = v;
    __syncthreads();
    int nn = t >> 3, kc = (t & 7) << 2;
    u16x4 o;
#pragma unroll
    for (int j = 0; j < 4; ++j) o[j] = f2bf(lds[kc + j][nn]);
    *(u16x4*)(out + (size_t)(n0 + nn) * K + k0 + kc) = o;
}

// ---------------- GEMM 128x128 tile, BK=64, bf16 MFMA ----------------
// EPI 0: QKV scatter (V written TRANSPOSED [bh][d][s]). EPI 1: proj+residual -> bf16 tmp.
template <int EPI>
__global__ __launch_bounds__(256) void k_gemm(
    const unsigned short* __restrict__ A, const unsigned short* __restrict__ Bt,
    int M, int N, int K, const float* __restrict__ bias,
    unsigned short* __restrict__ Qb, unsigned short* __restrict__ Kb,
    unsigned short* __restrict__ Vtb,
    const float* __restrict__ xres, unsigned short* __restrict__ outb) {
    __shared__ char smem[32768];
    char* As = smem;
    char* Bs = smem + 16384;
    int nbt = N >> 7;
    int mb = blockIdx.x / nbt, nbi = blockIdx.x % nbt;
    int m0 = mb << 7, n0 = nbi << 7;
    int tid = threadIdx.x, lane = tid & 63, wave = tid >> 6;
    int wr = wave >> 1, wc = wave & 1;

    f32x4 acc[4][4];
    f32x4 zero = {0.f, 0.f, 0.f, 0.f};
#pragma unroll
    for (int a = 0; a < 4; ++a)
#pragma unroll
        for (int b = 0; b < 4; ++b) acc[a][b] = zero;

    for (int kt = 0; kt < K; kt += 64) {
        __syncthreads();
#pragma unroll
        for (int j = 0; j < 4; ++j) {
            int la = (((wave << 2) + j) << 10) + lane * 16;
            int r = la >> 7, cb = la & 127;
            int cbs = cb ^ ((r & 7) << 4);
            gload16((const char*)(A + (size_t)(m0 + r) * K + kt) + cbs,
                    As + (((wave << 2) + j) << 10));
            gload16((const char*)(Bt + (size_t)(n0 + r) * K + kt) + cbs,
                    Bs + (((wave << 2) + j) << 10));
        }
        asm volatile("s_waitcnt vmcnt(0)" ::: "memory");
        __syncthreads();

        bf16x8 af[4][2], bfr[4][2];
#pragma unroll
        for (int rf = 0; rf < 4; ++rf)
#pragma unroll
            for (int c = 0; c < 2; ++c) {
                int row = (wr << 6) + (rf << 4) + (lane & 15);
                int col = (c << 6) + ((lane >> 4) << 4);
                af[rf][c] = *(const bf16x8*)(As + row * 128 + (col ^ ((row & 7) << 4)));
                int rowb = (wc << 6) + (rf << 4) + (lane & 15);
                bfr[rf][c] = *(const bf16x8*)(Bs + rowb * 128 + (col ^ ((rowb & 7) << 4)));
            }
#pragma unroll
        for (int rf = 0; rf < 4; ++rf)
#pragma unroll
            for (int nf = 0; nf < 4; ++nf)
#pragma unroll
                for (int c = 0; c < 2; ++c)
                    acc[rf][nf] = __builtin_amdgcn_mfma_f32_16x16x32_bf16(
                        af[rf][c], bfr[nf][c], acc[rf][nf], 0, 0, 0);
    }

#pragma unroll
    for (int rf = 0; rf < 4; ++rf)
#pragma unroll
        for (int nf = 0; nf < 4; ++nf) {
            int row0 = m0 + (wr << 6) + (rf << 4) + ((lane >> 4) << 2);
            int col = n0 + (wc << 6) + (nf << 4) + (lane & 15);
            float bv = bias[col];
            if (EPI == 0) {
                int reg = col >> 9, hd = col & 511;
                int h = hd >> 6, d = hd & 63;
                int b = row0 >> 12, s0 = row0 & 4095;
                if (reg == 2) {
                    u16x4 o4;
#pragma unroll
                    for (int i = 0; i < 4; ++i) o4[i] = f2bf(acc[rf][nf][i] + bv);
                    *(u16x4*)(Vtb + ((size_t)((b << 3) + h) * 64 + d) * 4096 + s0) = o4;
                } else {
#pragma unroll
                    for (int i = 0; i < 4; ++i) {
                        float v = acc[rf][nf][i] + bv;
                        size_t idx = ((size_t)((b << 3) + h) * Sv + s0 + i) * Dv + d;
                        if (reg == 0) Qb[idx] = f2bf(v * QSCALE);
                        else          Kb[idx] = f2bf(v);
                    }
                }
            } else {
#pragma unroll
                for (int i = 0; i < 4; ++i) {
                    int row = row0 + i;
                    float v = acc[rf][nf][i] + bv + xres[(size_t)row * N + col];
                    outb[(size_t)row * N + col] = f2bf(v);
                }
            }
        }
}

// ---------------- flash attention: 64q/wave, shared staging, counted vmcnt -----
// KV-split x2 (2048 kv/block = 64 chunks of 32). Per chunk: 8 gload16 split 2/wave;
// vmcnt(2)+s_barrier; compute. 3 LDS buffers x (K 4KB [32kv][128B] | V 4KB [64d][64B]).
// NOTE: min-waves stays 2 — forcing 4 caps VGPR at 128 -> scratch spills (R7).
// NOTE: do NOT fuse the merge here — the required device-scope __threadfence()
// invalidates L2 per block and destroyed KV reuse (R14: 84.5 -> 199 us).
__global__ __launch_bounds__(256, 2) void k_attn(const unsigned short* __restrict__ Qb,
                                                 const unsigned short* __restrict__ Kb,
                                                 const unsigned short* __restrict__ Vtb,
                                                 unsigned short* __restrict__ po,
                                                 float* __restrict__ pl) {
    __shared__ char smem[24576];
    int bid = blockIdx.x;
    int wg = ((bid & 7) << 6) + (bid >> 3);  // bijective XCD swizzle (nwg=512)
    int half = wg & 1, qblk = (wg >> 1) & 15, bh = wg >> 5;
    int tid = threadIdx.x, lane = tid & 63, wave = tid >> 6;
    int l31 = lane & 31, hh = lane >> 5;
    int qbase = (qblk << 8) + (wave << 6);  // 256 q/block, 64 q/wave
    int kvbase = half << 11;                // 2048 kv per block
    const int NCH = 64;                     // 64 chunks of 32 kv

    const char* Kbase = (const char*)(Kb + (size_t)bh * Sv * Dv + (size_t)kvbase * Dv);
    const char* Vtbase = (const char*)(Vtb + (size_t)bh * Dv * Sv + kvbase);

    bf16x8 qf[2][4];
#pragma unroll
    for (int qs = 0; qs < 2; ++qs)
#pragma unroll
        for (int tp = 0; tp < 4; ++tp)
            qf[qs][tp] = *(const bf16x8*)(Qb + ((size_t)bh * Sv + qbase + (qs << 5) + l31) * Dv +
                                          (tp << 4) + (hh << 3));

    const char* src0;
    const char* src1;
    size_t st0, st1;
    int d0, d1;
    {
        int j0 = wave << 1, j1 = j0 + 1;
        if (j0 < 4) {
            int lo0 = (j0 << 10) + lane * 16, r0 = lo0 >> 7, cb0 = lo0 & 127;
            src0 = Kbase + (size_t)r0 * 128 + (cb0 ^ ((r0 & 7) << 4));
            st0 = 4096; d0 = j0 << 10;
            int lo1 = (j1 << 10) + lane * 16, r1 = lo1 >> 7, cb1 = lo1 & 127;
            src1 = Kbase + (size_t)r1 * 128 + (cb1 ^ ((r1 & 7) << 4));
            st1 = 4096; d1 = j1 << 10;
        } else {
            int lo0 = ((j0 - 4) << 10) + lane * 16, r0 = lo0 >> 6, cb0 = lo0 & 63;
            src0 = Vtbase + (size_t)r0 * 8192 + (cb0 ^ ((r0 & 6) << 3));
            st0 = 64; d0 = 4096 + ((j0 - 4) << 10);
            int lo1 = ((j1 - 4) << 10) + lane * 16, r1 = lo1 >> 6, cb1 = lo1 & 63;
            src1 = Vtbase + (size_t)r1 * 8192 + (cb1 ^ ((r1 & 6) << 3));
            st1 = 64; d1 = 4096 + ((j1 - 4) << 10);
        }
    }

    int koff[4], voff[4];
#pragma unroll
    for (int tp = 0; tp < 4; ++tp)
        koff[tp] = l31 * 128 + (((tp << 5) + (hh << 4)) ^ ((l31 & 7) << 4));
#pragma unroll
    for (int tl = 0; tl < 2; ++tl)
#pragma unroll
        for (int dt = 0; dt < 2; ++dt) {
            int row = (dt << 5) + l31;
            int col = (tl << 5) + (hh << 4);
            voff[tl * 2 + dt] = row * 64 + (col ^ ((row & 6) << 3));
        }

    f32x16 o[2][2];
#pragma unroll
    for (int qs = 0; qs < 2; ++qs)
#pragma unroll
        for (int dt = 0; dt < 2; ++dt)
#pragma unroll
            for (int r = 0; r < 16; ++r) o[qs][dt][r] = 0.f;
    float lsum[2] = {0.f, 0.f};

    gload16(src0, smem + d0);
    gload16(src1, smem + d1);
    gload16(src0 + st0, smem + 8192 + d0);
    gload16(src1 + st1, smem + 8192 + d1);

#define COMPUTE_CHUNK(KSP, VSP)                                                          \
    {                                                                                    \
        bf16x8 kf[4], vf[4];                                                             \
        _Pragma("unroll") for (int tp = 0; tp < 4; ++tp)                                 \
            kf[tp] = *(const bf16x8*)((KSP) + koff[tp]);                                 \
        _Pragma("unroll") for (int i = 0; i < 4; ++i)                                    \
            vf[i] = *(const bf16x8*)((VSP) + voff[i]);                                   \
        _Pragma("unroll") for (int qs = 0; qs < 2; ++qs) {                               \
            f32x16 sc;                                                                   \
            _Pragma("unroll") for (int r = 0; r < 16; ++r) sc[r] = C0;                   \
            __builtin_amdgcn_s_setprio(1);                                               \
            _Pragma("unroll") for (int tp = 0; tp < 4; ++tp)                             \
                sc = __builtin_amdgcn_mfma_f32_32x32x16_bf16(kf[tp], qf[qs][tp], sc, 0, 0, 0); \
            __builtin_amdgcn_s_setprio(0);                                               \
            _Pragma("unroll") for (int r = 0; r < 16; ++r) sc[r] = EXP2F(sc[r]);         \
            float s0 = (sc[0] + sc[1]) + (sc[2] + sc[3]);                                \
            float s1 = (sc[4] + sc[5]) + (sc[6] + sc[7]);                                \
            float s2 = (sc[8] + sc[9]) + (sc[10] + sc[11]);                              \
            float s3 = (sc[12] + sc[13]) + (sc[14] + sc[15]);                            \
            lsum[qs] += (s0 + s1) + (s2 + s3);                                           \
            unsigned int W[8];                                                           \
            _Pragma("unroll") for (int i = 0; i < 8; ++i)                                \
                W[i] = cvtpk(sc[2 * i], sc[2 * i + 1]);                                  \
            _Pragma("unroll") for (int tl = 0; tl < 2; ++tl) {                           \
                unsigned int a1 = W[4 * tl], b1 = W[4 * tl + 2];                         \
                unsigned int a2 = W[4 * tl + 1], b2 = W[4 * tl + 3];                     \
                asm volatile("v_permlane32_swap_b32 %0, %1" : "+v"(a1), "+v"(b1));       \
                asm volatile("v_permlane32_swap_b32 %0, %1" : "+v"(a2), "+v"(b2));       \
                u32x4v uu;                                                               \
                uu[0] = a1; uu[1] = a2; uu[2] = b1; uu[3] = b2;                          \
                bf16x8 pf = __builtin_bit_cast(bf16x8, uu);                              \
                __builtin_amdgcn_s_setprio(1);                                           \
                _Pragma("unroll") for (int dt = 0; dt < 2; ++dt)                         \
                    o[qs][dt] = __builtin_amdgcn_mfma_f32_32x32x16_bf16(                 \
                        vf[tl * 2 + dt], pf, o[qs][dt], 0, 0, 0);                        \
                __builtin_amdgcn_s_setprio(0);                                           \
            }                                                                            \
        }                                                                                \
    }

    int cur = 0;
    for (int kt = 0; kt < NCH - 1; ++kt) {
        asm volatile("s_waitcnt vmcnt(2)\n\ts_barrier" ::: "memory");
        if (kt + 2 < NCH) {
            int tb = cur + 2; if (tb >= 3) tb -= 3;
            gload16(src0 + (size_t)(kt + 2) * st0, smem + tb * 8192 + d0);
            gload16(src1 + (size_t)(kt + 2) * st1, smem + tb * 8192 + d1);
        }
        char* cbuf = smem + cur * 8192;
        COMPUTE_CHUNK(cbuf, cbuf + 4096);
        cur = (cur + 1 == 3) ? 0 : cur + 1;
    }
    asm volatile("s_waitcnt vmcnt(0)\n\ts_barrier" ::: "memory");
    {
        char* cbuf = smem + cur * 8192;
        COMPUTE_CHUNK(cbuf, cbuf + 4096);
    }
#undef COMPUTE_CHUNK

#pragma unroll
    for (int qs = 0; qs < 2; ++qs) {
        float ls = lsum[qs] + __shfl_xor(lsum[qs], 32, 64);
        int qrow = qbase + (qs << 5) + l31;
        if (!hh) pl[((size_t)half * 16 + bh) * Sv + qrow] = ls;
        size_t obase = (((size_t)half * 16 + bh) * Sv + qrow) * 64;
#pragma unroll
        for (int dt = 0; dt < 2; ++dt)
#pragma unroll
            for (int rp = 0; rp < 8; ++rp) {
                int r = rp << 1;
                int d = (dt << 5) + (r & 3) + ((r >> 2) << 3) + (hh << 2);
                unsigned int w = cvtpk(o[qs][dt][r], o[qs][dt][r + 1]);
                *(unsigned int*)(po + obase + d) = w;
            }
    }
}

// ---------------- merge: ctx = (o0+o1)/(l0+l1), bf16 out ----------------
__global__ __launch_bounds__(256) void k_merge(const unsigned short* __restrict__ po,
                                               const float* __restrict__ pl,
                                               unsigned short* __restrict__ ctx) {
    int t = blockIdx.x * 256 + threadIdx.x;  // 16*4096*8 threads
    int d8 = t & 7, s = (t >> 3) & 4095, bh = t >> 15;
    int b = bh >> 3, h = bh & 7;
    size_t r0 = ((size_t)bh * 4096 + s) * 64 + (d8 << 3);
    size_t r1 = r0 + (size_t)16 * 4096 * 64;
    u16x8 pa = *(const u16x8*)(po + r0);
    u16x8 pb = *(const u16x8*)(po + r1);
    float inv = 1.f / (pl[(size_t)bh * 4096 + s] + pl[(size_t)16 * 4096 + bh * 4096 + s]);
    u32x4v w;
#pragma unroll
    for (int j = 0; j < 4; ++j) {
        float lo = (b2f(pa[2 * j]) + b2f(pb[2 * j])) * inv;
        float hi = (b2f(pa[2 * j + 1]) + b2f(pb[2 * j + 1])) * inv;
        w[j] = cvtpk(lo, hi);
    }
    *(u32x4v*)(ctx + ((size_t)b * 4096 + s) * 512 + (h << 6) + (d8 << 3)) = w;
}

// ---------------- LayerNorm (1 wave / row of 512, bf16 in, fp32 out) ----------------
__global__ __launch_bounds__(256) void k_ln(const unsigned short* __restrict__ in,
                                            const float* __restrict__ g,
                                            const float* __restrict__ bta,
                                            float* __restrict__ out) {
    int wave = threadIdx.x >> 6, lane = threadIdx.x & 63;
    size_t row = (size_t)blockIdx.x * 4 + wave;
    u16x8 raw = *(const u16x8*)(in + row * 512 + lane * 8);
    float v[8];
    float s = 0.f, q = 0.f;
#pragma unroll
    for (int j = 0; j < 8; ++j) {
        v[j] = b2f(raw[j]);
        s += v[j];
        q += v[j] * v[j];
    }
#pragma unroll
    for (int off = 1; off < 64; off <<= 1) {
        s += __shfl_xor(s, off, 64);
        q += __shfl_xor(q, off, 64);
    }
    float mu = s * (1.f / 512.f);
    float var = q * (1.f / 512.f) - mu * mu;
    float rs = rsqrtf(var + 1e-5f);
    int c = lane * 8;
    float4v o0, o1;
#pragma unroll
    for (int j = 0; j < 4; ++j) {
        o0[j] = (v[j] - mu) * rs * g[c + j] + bta[c + j];
        o1[j] = (v[4 + j] - mu) * rs * g[c + 4 + j] + bta[c + 4 + j];
    }
    *(float4v*)(out + row * 512 + c) = o0;
    *(float4v*)(out + row * 512 + c + 4) = o1;
}

extern "C" void kernel_launch(void* const* d_in, const int* in_sizes, int n_in,
                              void* d_out, int out_size, void* d_ws, size_t ws_size,
                              hipStream_t stream) {
    const float* x     = (const float*)d_in[0];
    const float* qkv_w = (const float*)d_in[1];
    const float* qkv_b = (const float*)d_in[2];
    const float* out_w = (const float*)d_in[3];
    const float* out_b = (const float*)d_in[4];
    const float* ln_g  = (const float*)d_in[5];
    const float* ln_b  = (const float*)d_in[6];
    float* out = (float*)d_out;
    char* ws = (char*)d_ws;

    // layout (peak ~45 MB):
    unsigned short* owT   = (unsigned short*)(ws);              // 0.5 MB  [until gemm1]
    unsigned short* wqkvT = (unsigned short*)(ws + 524288);     // 1.5 MB  [until gemm0]
    unsigned short* Qb    = (unsigned short*)(ws + 2097152);    // 8 MB    [until attn]
    unsigned short* Kb    = (unsigned short*)(ws + 10485760);   // 8 MB    [until attn]
    unsigned short* Vtb   = (unsigned short*)(ws + 18874368);   // 8 MB    [until attn]
    unsigned short* xb    = (unsigned short*)(ws + 27262976);   // 8 MB    [until gemm0]
    unsigned short* po    = (unsigned short*)(ws + 27262976);   // 16 MB   [attn..merge, over xb]
    float* pl             = (float*)(ws + 60817408);            // 0.5 MB
    unsigned short* ctxb  = (unsigned short*)(ws + 2097152);    // 8 MB    [merge..gemm1, over Qb]
    unsigned short* tmpb  = (unsigned short*)(ws + 10485760);   // 8 MB    [gemm1..ln, over Kb]

    k_prep<<<3072, 256, 0, stream>>>(x, xb, qkv_w, wqkvT, out_w, owT);
    k_gemm<0><<<(Mv / 128) * (N3v / 128), 256, 0, stream>>>(
        xb, wqkvT, Mv, N3v, Ev, qkv_b, Qb, Kb, Vtb, nullptr, nullptr);
    k_attn<<<512, 256, 0, stream>>>(Qb, Kb, Vtb, po, pl);
    k_merge<<<2048, 256, 0, stream>>>(po, pl, ctxb);
    k_gemm<1><<<(Mv / 128) * (Ev / 128), 256, 0, stream>>>(
        ctxb, owT, Mv, Ev, Ev, out_b, nullptr, nullptr, nullptr, x, tmpb);
    k_ln<<<Mv / 4, 256, 0, stream>>>(tmpb, ln_g, ln_b, out);
}